// Round 1
// baseline (342.613 us; speedup 1.0000x reference)
//
#include <hip/hip_runtime.h>
#include <math.h>

#define LSEQ 4096
#define NFFT 8192
#define NF   512     // kept frequency bins
#define NF2  1024    // 2*NF (cos/sin interleaved)
#define NH   768
#define NBH  6144    // 8*768
#define MROWS 6912   // NBH + NH (x rows + k rows share stage-A GEMM)

typedef __attribute__((ext_vector_type(8))) short short8;   // 8 bf16 (4 VGPRs)
typedef __attribute__((ext_vector_type(4))) float floatx4;  // MFMA accumulator

__device__ __forceinline__ unsigned short f2bf(float f) {
    unsigned int u = __float_as_uint(f);
    u += 0x7fff + ((u >> 16) & 1);       // round-to-nearest-even
    return (unsigned short)(u >> 16);
}

// -------- fused trig tables: T1[f2][n] and T2[n][f2], bf16 -----------------
__global__ void build_tables(unsigned short* __restrict__ T1,
                             unsigned short* __restrict__ T2) {
    __shared__ unsigned short tile[64][66];   // pad 66: transpose-read conflict-free
    const int t = threadIdx.x;
    const int F0 = blockIdx.x * 64;
    const int N0 = blockIdx.y * 64;
#pragma unroll
    for (int i = 0; i < 16; ++i) {
        int r = (t >> 6) + i * 4;
        int c = t & 63;
        int f2 = F0 + r, n = N0 + c;
        int f = f2 >> 1;
        int p = (f * n) & (NFFT - 1);
        float th = (float)p * (float)(2.0 * M_PI / (double)NFFT);
        float s, cc;
        sincosf(th, &s, &cc);
        unsigned short v = f2bf((f2 & 1) ? s : cc);
        T1[(size_t)f2 * LSEQ + n] = v;
        tile[r][c] = v;
    }
    __syncthreads();
#pragma unroll
    for (int i = 0; i < 16; ++i) {
        int r = (t >> 6) + i * 4;
        int c = t & 63;
        T2[(size_t)(N0 + r) * NF2 + F0 + c] = tile[c][r];
    }
}

// -------- fp32 -> bf16 pack of [x ; k] into one [6912, 4096] matrix --------
__global__ void tobf16(const float* __restrict__ x, const float* __restrict__ kk,
                       unsigned short* __restrict__ o) {
    size_t e = ((size_t)blockIdx.x * 256 + threadIdx.x) * 4;
    const size_t XN = (size_t)NBH * LSEQ;
    const float* s = (e < XN) ? (x + e) : (kk + (e - XN));
    float4 v = *(const float4*)s;
    unsigned int lo = (unsigned int)f2bf(v.x) | ((unsigned int)f2bf(v.y) << 16);
    unsigned int hi = (unsigned int)f2bf(v.z) | ((unsigned int)f2bf(v.w) << 16);
    *(uint2*)(o + e) = make_uint2(lo, hi);
}

// -------- pipelined bf16 GEMM: C[M,N] = A[M,K] * B^T[N,K], fp32 out --------
// Register-prefetch + LDS double-buffer, one barrier per K-iter:
//   loads for tile k+1 issue BEFORE tile k's MFMAs (vmcnt wait lands at the
//   ds_write to the other buffer), so global latency overlaps the MFMA phase
//   instead of sitting in the vmcnt(0)+s_barrier drain (R2/R3: ~1230 cyc/iter
//   vs ~310 cyc MFMA floor).
__global__ __launch_bounds__(256) void gemm_bt(
    const unsigned short* __restrict__ A,   // [M,K] bf16
    const unsigned short* __restrict__ B,   // [N,K] bf16 (transposed operand)
    float* __restrict__ C,                  // [M,N] fp32
    int M, int N, int K)
{
    __shared__ __align__(16) unsigned short As[2][128 * 32];
    __shared__ __align__(16) unsigned short Bs[2][128 * 32];
    const int t = threadIdx.x;
    const int w = t >> 6, l = t & 63;
    const int m0 = blockIdx.y * 128, n0 = blockIdx.x * 128;
    const int wm = (w >> 1) * 64, wn = (w & 1) * 64;
    const int lq = l >> 4, lr = l & 15;

    floatx4 acc[4][4];
#pragma unroll
    for (int i = 0; i < 4; ++i)
#pragma unroll
        for (int j = 0; j < 4; ++j)
            acc[i][j] = (floatx4){0.f, 0.f, 0.f, 0.f};

    // staging: 2 x 16B chunks per operand per thread (8 KB tile / 256 thr)
    const int q0 = t, q1 = t + 256;
    const int r0 = q0 >> 2, e0 = (q0 & 3) * 8;
    const int r1 = q1 >> 2, e1 = (q1 & 3) * 8;
    const unsigned short* pa0 = A + (size_t)(m0 + r0) * K + e0;
    const unsigned short* pa1 = A + (size_t)(m0 + r1) * K + e1;
    const unsigned short* pb0 = B + (size_t)(n0 + r0) * K + e0;
    const unsigned short* pb1 = B + (size_t)(n0 + r1) * K + e1;

    // prologue: tile 0 -> regs -> LDS buf0
    uint4 ra0 = *(const uint4*)pa0;
    uint4 ra1 = *(const uint4*)pa1;
    uint4 rb0 = *(const uint4*)pb0;
    uint4 rb1 = *(const uint4*)pb1;
    *(uint4*)(As[0] + q0 * 8) = ra0;
    *(uint4*)(As[0] + q1 * 8) = ra1;
    *(uint4*)(Bs[0] + q0 * 8) = rb0;
    *(uint4*)(Bs[0] + q1 * 8) = rb1;
    __syncthreads();

    int cur = 0;
    for (int k0 = 32; k0 < K; k0 += 32) {
        // issue next tile's global loads first (overlap with MFMAs below)
        ra0 = *(const uint4*)(pa0 + k0);
        ra1 = *(const uint4*)(pa1 + k0);
        rb0 = *(const uint4*)(pb0 + k0);
        rb1 = *(const uint4*)(pb1 + k0);

        short8 af[4], bfv[4];
#pragma unroll
        for (int i = 0; i < 4; ++i)
            af[i] = *(const short8*)(As[cur] + (wm + 16 * i + lr) * 32 + lq * 8);
#pragma unroll
        for (int j = 0; j < 4; ++j)
            bfv[j] = *(const short8*)(Bs[cur] + (wn + 16 * j + lr) * 32 + lq * 8);
#pragma unroll
        for (int i = 0; i < 4; ++i)
#pragma unroll
            for (int j = 0; j < 4; ++j)
                acc[i][j] = __builtin_amdgcn_mfma_f32_16x16x32_bf16(af[i], bfv[j], acc[i][j], 0, 0, 0);

        const int nxt = cur ^ 1;
        *(uint4*)(As[nxt] + q0 * 8) = ra0;   // vmcnt wait lands here, post-MFMA
        *(uint4*)(As[nxt] + q1 * 8) = ra1;
        *(uint4*)(Bs[nxt] + q0 * 8) = rb0;
        *(uint4*)(Bs[nxt] + q1 * 8) = rb1;
        __syncthreads();
        cur = nxt;
    }

    // last tile
    {
        short8 af[4], bfv[4];
#pragma unroll
        for (int i = 0; i < 4; ++i)
            af[i] = *(const short8*)(As[cur] + (wm + 16 * i + lr) * 32 + lq * 8);
#pragma unroll
        for (int j = 0; j < 4; ++j)
            bfv[j] = *(const short8*)(Bs[cur] + (wn + 16 * j + lr) * 32 + lq * 8);
#pragma unroll
        for (int i = 0; i < 4; ++i)
#pragma unroll
            for (int j = 0; j < 4; ++j)
                acc[i][j] = __builtin_amdgcn_mfma_f32_16x16x32_bf16(af[i], bfv[j], acc[i][j], 0, 0, 0);
    }

    // C/D layout: col = lane&15, row = (lane>>4)*4 + reg  [verified m89/m91]
#pragma unroll
    for (int i = 0; i < 4; ++i)
#pragma unroll
        for (int j = 0; j < 4; ++j)
#pragma unroll
            for (int r = 0; r < 4; ++r) {
                int row = m0 + wm + 16 * i + lq * 4 + r;
                int col = n0 + wn + 16 * j + lr;
                C[(size_t)row * N + col] = acc[i][j][r];
            }
}

// -------- combine: complex multiply + irfft scaling -> bf16 AB -------------
__global__ void combine(const float* __restrict__ C1, unsigned short* __restrict__ AB) {
    int idx = blockIdx.x * blockDim.x + threadIdx.x;   // bh*512 + f
    int bh = idx >> 9;
    int f = idx & (NF - 1);
    int h = bh % NH;
    const float* xc = C1 + (size_t)bh * NF2 + 2 * f;
    const float* kc = C1 + (size_t)(NBH + h) * NF2 + 2 * f;
    float Xre = xc[0], Xim = -xc[1];
    float Kre = kc[0], Kim = -kc[1];
    float s = (f == 0 ? 1.0f : 2.0f) * (1.0f / (float)NFFT);
    float Av = s * (Xre * Kre - Xim * Kim);
    float Bv = -(s * (Xre * Kim + Xim * Kre));
    unsigned int packed = (unsigned int)f2bf(Av) | ((unsigned int)f2bf(Bv) << 16);
    *(unsigned int*)(AB + (size_t)bh * NF2 + 2 * f) = packed;
}

extern "C" void kernel_launch(void* const* d_in, const int* in_sizes, int n_in,
                              void* d_out, int out_size, void* d_ws, size_t ws_size,
                              hipStream_t stream) {
    const float* x = (const float*)d_in[0];   // [8,768,4096]
    const float* k = (const float*)d_in[1];   // [768,4096]
    float* y = (float*)d_out;

    // ws layout (28.6 MB; 45.1 MB proven available in R1):
    unsigned short* T1 = (unsigned short*)d_ws;                 // [1024,4096] bf16
    unsigned short* T2 = T1 + (size_t)NF2 * LSEQ;               // [4096,1024] bf16
    unsigned short* AB = T2 + (size_t)LSEQ * NF2;               // [6144,1024] bf16

    // d_out doubles as scratch (85 MB of 100.66 MB) until stage B overwrites:
    unsigned short* Abm = (unsigned short*)d_out;               // [6912,4096] bf16, 56.6 MB
    float* C1 = (float*)((char*)d_out + (size_t)MROWS * LSEQ * 2); // [6912,1024] f32, 28.3 MB

    const int blk = 256;
    hipLaunchKernelGGL(build_tables, dim3(NF2 / 64, LSEQ / 64), dim3(blk), 0, stream, T1, T2);
    hipLaunchKernelGGL(tobf16, dim3((MROWS * LSEQ / 4) / blk), dim3(blk), 0, stream, x, k, Abm);
    // Stage A: [6912,4096] x [4096,1024] -> C1 (X and K spectra together)
    hipLaunchKernelGGL(gemm_bt, dim3(NF2 / 128, MROWS / 128), dim3(blk), 0, stream,
                       Abm, T1, C1, MROWS, NF2, LSEQ);
    hipLaunchKernelGGL(combine, dim3((NBH * NF) / blk), dim3(blk), 0, stream, C1, AB);
    // Stage B: [6144,1024] x [1024,4096] -> y
    hipLaunchKernelGGL(gemm_bt, dim3(LSEQ / 128, NBH / 128), dim3(blk), 0, stream,
                       AB, T2, y, NBH, LSEQ, NF2);
}